// Round 1
// baseline (749.161 us; speedup 1.0000x reference)
//
#include <hip/hip_runtime.h>
#include <math.h>

#define M_LEN 40000
#define B_SZ 16
#define K_TAPS 201
#define T_HALF 100
#define L_OUT 39800          // M_LEN - K_TAPS + 1
#define TL 128               // outputs per block
#define NTILES 311           // ceil(L_OUT / TL)
#define NP 328               // TL + K_TAPS - 1 : series positions per tile
#define NPP 329              // odd-padded stride
#define NPX 332              // NP + 4 : x positions (shifts +-2)
#define NPXP 333             // odd-padded stride

__global__ __launch_bounds__(128) void snse_kernel(
    const float* __restrict__ g_xr, const float* __restrict__ g_xi,
    const float* __restrict__ g_ti, const float* __restrict__ g_c00,
    const float* __restrict__ g_wx, const float* __restrict__ g_wc,
    const float* __restrict__ g_wr, const float* __restrict__ g_wi,
    float* __restrict__ g_out)
{
    __shared__ float s_xr[2][NPXP], s_xi[2][NPXP];
    __shared__ float s_ps[2][NPP];
    __shared__ float s_qr[NPP], s_qi[NPP];
    __shared__ float s_Ar[4][2][NPP], s_Ai[4][2][NPP];
    __shared__ float s_Br[4][2][NPP], s_Bi[4][2][NPP];

    const int tid = threadIdx.x;
    const int b   = blockIdx.y;
    const int l0  = blockIdx.x * TL;

    const float tdb    = g_ti[b * 4 + 0];
    const float P      = expf(tdb * 0.23025850929940457f) * 0.5f; // 10^(t/10)/2
    const float sP     = sqrtf(P);
    const float inv_sP = 1.0f / sP;
    const float C00    = g_c00[0];

    // ---- stage scaled x: positions m = l0-2 .. l0+NPX-3 (wrapped mod M) ----
    for (int idx = tid; idx < 2 * NPX; idx += 128) {
        int pidx = idx >> 1, nn = idx & 1;
        int m = l0 - 2 + pidx;
        int mw = m < 0 ? m + M_LEN : (m >= M_LEN ? m - M_LEN : m);
        int g = (b * M_LEN + mw) * 2 + nn;
        s_xr[nn][pidx] = g_xr[g] * sP;
        s_xi[nn][pidx] = g_xi[g] * sP;
    }
    __syncthreads();

    // ---- stage conv series per position m = l0 + idx ----
    for (int idx = tid; idx < NP; idx += 128) {
        const int ix = idx + 2; // x-array index of same position
        float x0r = s_xr[0][ix], x0i = s_xi[0][ix];
        float x1r = s_xr[1][ix], x1i = s_xi[1][ix];
        float p0 = x0r * x0r + x0i * x0i;
        float p1 = x1r * x1r + x1i * x1i;
        s_ps[0][idx] = 2.f * p0 + p1;
        s_ps[1][idx] = 2.f * p1 + p0;
        // q[0] = x0 * conj(x1); q[1] = conj(q[0]) (not stored)
        s_qr[idx] = x0r * x1r + x0i * x1i;
        s_qi[idx] = x0i * x1r - x0r * x1i;
        const int ss[4] = {-2, -1, 1, 2};
#pragma unroll
        for (int si = 0; si < 4; ++si) {
            int jx = ix - ss[si]; // x[m - s]
            float a0r = s_xr[0][jx], a0i = s_xi[0][jx];
            float a1r = s_xr[1][jx], a1i = s_xi[1][jx];
            // U_n = x[n] * conj(xs[n])
            float U0r = x0r * a0r + x0i * a0i;
            float U0i = x0i * a0r - x0r * a0i;
            float U1r = x1r * a1r + x1i * a1i;
            float U1i = x1i * a1r - x1r * a1i;
            // A[n] = 2*U_n + U_{1-n}
            s_Ar[si][0][idx] = 2.f * U0r + U1r;
            s_Ai[si][0][idx] = 2.f * U0i + U1i;
            s_Ar[si][1][idx] = 2.f * U1r + U0r;
            s_Ai[si][1][idx] = 2.f * U1i + U0i;
            // B[n] = x[n] * conj(xs[1-n])
            s_Br[si][0][idx] = x0r * a1r + x0i * a1i;
            s_Bi[si][0][idx] = x0i * a1r - x0r * a1i;
            s_Br[si][1][idx] = x1r * a0r + x1i * a0i;
            s_Bi[si][1][idx] = x1i * a0r - x1r * a0i;
        }
    }
    __syncthreads();

    // ---- main conv loop: thread owns outputs l0+r and l0+r+1, channel nn ----
    const int hl = tid >> 1;
    const int nn = tid & 1;
    const int r  = hl << 1;

    float acc_ix[2] = {0.f, 0.f};
    float acc_qr[2] = {0.f, 0.f};
    float acc_qi[2] = {0.f, 0.f};
    float fAr[2][4] = {{0.f,0.f,0.f,0.f},{0.f,0.f,0.f,0.f}};
    float fAi[2][4] = {{0.f,0.f,0.f,0.f},{0.f,0.f,0.f,0.f}};
    float fBr[2][4] = {{0.f,0.f,0.f,0.f},{0.f,0.f,0.f,0.f}};
    float fBi[2][4] = {{0.f,0.f,0.f,0.f},{0.f,0.f,0.f,0.f}};

    // rolling previous values (position r + j)
    float p_ps = s_ps[nn][r];
    float p_qr = s_qr[r], p_qi = s_qi[r];
    float p_Ar[4], p_Ai[4], p_Br[4], p_Bi[4];
#pragma unroll
    for (int si = 0; si < 4; ++si) {
        p_Ar[si] = s_Ar[si][nn][r];
        p_Ai[si] = s_Ai[si][nn][r];
        p_Br[si] = s_Br[si][nn][r];
        p_Bi[si] = s_Bi[si][nn][r];
    }

    for (int j = 0; j < K_TAPS; ++j) {
        const float w_x = g_wx[j];          // uniform -> s_load
        const float w_c = g_wc[j];
        const int rj = r + j + 1;
        float c_ps = s_ps[nn][rj];
        float c_qr = s_qr[rj], c_qi = s_qi[rj];
        acc_ix[0] += w_x * p_ps;  acc_ix[1] += w_x * c_ps;
        acc_qr[0] += w_c * p_qr;  acc_qr[1] += w_c * c_qr;
        acc_qi[0] += w_c * p_qi;  acc_qi[1] += w_c * c_qi;
        p_ps = c_ps; p_qr = c_qr; p_qi = c_qi;
#pragma unroll
        for (int si = 0; si < 4; ++si) {
            const float w_r = g_wr[si * K_TAPS + j];
            const float w_i = g_wi[si * K_TAPS + j];
            float cAr = s_Ar[si][nn][rj], cAi = s_Ai[si][nn][rj];
            float cBr = s_Br[si][nn][rj], cBi = s_Bi[si][nn][rj];
            fAr[0][si] += w_r * p_Ar[si] - w_i * p_Ai[si];
            fAi[0][si] += w_r * p_Ai[si] + w_i * p_Ar[si];
            fAr[1][si] += w_r * cAr - w_i * cAi;
            fAi[1][si] += w_r * cAi + w_i * cAr;
            fBr[0][si] += w_r * p_Br[si] - w_i * p_Bi[si];
            fBi[0][si] += w_r * p_Bi[si] + w_i * p_Br[si];
            fBr[1][si] += w_r * cBr - w_i * cBi;
            fBi[1][si] += w_r * cBi + w_i * cBr;
            p_Ar[si] = cAr; p_Ai[si] = cAi;
            p_Br[si] = cBr; p_Bi[si] = cBi;
        }
    }

    // zero-center-tap correction (zcv subtracts w[k/2] * center sample)
    {
        const float wx100 = g_wx[T_HALF];
        const float wc100 = g_wc[T_HALF];
#pragma unroll
        for (int o = 0; o < 2; ++o) {
            int mc = r + o + T_HALF;
            acc_ix[o] -= wx100 * s_ps[nn][mc];
            acc_qr[o] -= wc100 * s_qr[mc];
            acc_qi[o] -= wc100 * s_qi[mc];
        }
    }

    // ---- epilogue ----
    const int ssf[4] = {-2, -1, 1, 2};
#pragma unroll
    for (int o = 0; o < 2; ++o) {
        const int lrel = r + o;
        const int l = l0 + lrel;
        const int xc = lrel + T_HALF + 2; // x-array index of t+l
        float X0r = s_xr[0][xc], X0i = s_xi[0][xc];
        float X1r = s_xr[1][xc], X1i = s_xi[1][xc];
        float pw  = X0r * X0r + X0i * X0i + X1r * X1r + X1i * X1i;
        float phi = C00 * pw + 2.f * acc_ix[o];
        float sph, cph;
        __sincosf(phi, &sph, &cph);
        // qc for this channel (q[1] = conj(q[0]), real weights)
        float qcr = acc_qr[o];
        float qci = nn ? -acc_qi[o] : acc_qi[o];
        // base = x[t+l, nn], other = x[t+l, 1-nn]
        float br_ = nn ? X1r : X0r, bi_ = nn ? X1i : X0i;
        float or_ = nn ? X0r : X1r, oi_ = nn ? X0i : X1i;
        // ici = i * other * qc
        float ici_r = -(or_ * qci + oi_ * qcr);
        float ici_i =   or_ * qcr - oi_ * qci;
        // fwm = sum_si x[t+l-s, nn]*fA + x[t+l-s, 1-nn]*fB
        float fw_r = 0.f, fw_i = 0.f;
#pragma unroll
        for (int si = 0; si < 4; ++si) {
            int sx = xc - ssf[si];
            float xnr = s_xr[nn][sx],     xni = s_xi[nn][sx];
            float xor_ = s_xr[1 - nn][sx], xoi = s_xi[1 - nn][sx];
            fw_r += xnr * fAr[o][si] - xni * fAi[o][si]
                  + xor_ * fBr[o][si] - xoi * fBi[o][si];
            fw_i += xnr * fAi[o][si] + xni * fAr[o][si]
                  + xor_ * fBi[o][si] + xoi * fBr[o][si];
        }
        float out_r = br_ * cph - bi_ * sph + ici_r + fw_r;
        float out_i = br_ * sph + bi_ * cph + ici_i + fw_i;
        if (l < L_OUT) {
            int oidx = (((b * L_OUT) + l) * 2 + nn) * 2;
            g_out[oidx]     = out_r * inv_sP;
            g_out[oidx + 1] = out_i * inv_sP;
        }
    }
}

extern "C" void kernel_launch(void* const* d_in, const int* in_sizes, int n_in,
                              void* d_out, int out_size, void* d_ws, size_t ws_size,
                              hipStream_t stream) {
    const float* xr  = (const float*)d_in[0];
    const float* xi  = (const float*)d_in[1];
    const float* ti  = (const float*)d_in[2];
    const float* c00 = (const float*)d_in[3];
    const float* wx  = (const float*)d_in[4];
    const float* wc  = (const float*)d_in[5];
    const float* wr  = (const float*)d_in[6];
    const float* wi  = (const float*)d_in[7];
    float* out = (float*)d_out;

    dim3 grid(NTILES, B_SZ, 1);
    dim3 block(128, 1, 1);
    snse_kernel<<<grid, block, 0, stream>>>(xr, xi, ti, c00, wx, wc, wr, wi, out);
}

// Round 2
// 414.872 us; speedup vs baseline: 1.8058x; 1.8058x over previous
//
#include <hip/hip_runtime.h>
#include <math.h>

#define M_LEN 40000
#define B_SZ 16
#define K_TAPS 201
#define T_HALF 100
#define L_OUT 39800          // M_LEN - K_TAPS + 1
#define TL 256               // outputs per block (4 per thread-group)
#define NTILES 156           // ceil(L_OUT / TL)
#define NP 456               // TL + K_TAPS - 1 : series positions per tile
#define NPX 460              // NP + 4 : x positions (shifts +-2)
#define STR 464              // series stride in floats (mult of 4, %32==16)
#define NSER 36

// window element t in 0..6: t<4 -> P component, else C component
__device__ __forceinline__ float gw(const float4 P, const float4 C, int t) {
    switch (t) {
        case 0: return P.x; case 1: return P.y; case 2: return P.z; case 3: return P.w;
        case 4: return C.x; case 5: return C.y; case 6: return C.z; default: return C.w;
    }
}

// 4 taps x 4 outputs, real weights
__device__ __forceinline__ void conv4r(const float4 P, const float4 C,
                                       const float* w, float* acc) {
#pragma unroll
    for (int jj = 0; jj < 4; ++jj)
#pragma unroll
        for (int o = 0; o < 4; ++o)
            acc[o] = fmaf(w[jj], gw(P, C, jj + o), acc[o]);
}

// 4 taps x 4 outputs, complex series x complex weights
__device__ __forceinline__ void conv4c(const float4 Pr, const float4 Cr,
                                       const float4 Pi, const float4 Ci,
                                       const float* wr, const float* wi,
                                       float* ar, float* ai) {
#pragma unroll
    for (int jj = 0; jj < 4; ++jj)
#pragma unroll
        for (int o = 0; o < 4; ++o) {
            float vr = gw(Pr, Cr, jj + o);
            float vi = gw(Pi, Ci, jj + o);
            ar[o] = fmaf(wr[jj], vr, fmaf(-wi[jj], vi, ar[o]));
            ai[o] = fmaf(wr[jj], vi, fmaf( wi[jj], vr, ai[o]));
        }
}

__global__ __launch_bounds__(128, 1) void snse_kernel(
    const float* __restrict__ g_xr, const float* __restrict__ g_xi,
    const float* __restrict__ g_ti, const float* __restrict__ g_c00,
    const float* __restrict__ g_wx, const float* __restrict__ g_wc,
    const float* __restrict__ g_wr, const float* __restrict__ g_wi,
    float* __restrict__ g_out)
{
    // series layout: arr 0..1 = ps[ch], 2 = qr, 3 = qi,
    // 4+si*8 + {0,1}=Ar[ch], {2,3}=Ai[ch], {4,5}=Br[ch], {6,7}=Bi[ch]
    __shared__ __align__(16) float S[NSER * STR];
    __shared__ __align__(16) float s_xr[2][STR], s_xi[2][STR];

    const int tid = threadIdx.x;
    const int b   = blockIdx.y;
    const int l0  = blockIdx.x * TL;

    const float tdb    = g_ti[b * 4 + 0];
    const float P      = expf(tdb * 0.23025850929940457f) * 0.5f; // 10^(t/10)/2
    const float sP     = sqrtf(P);
    const float inv_sP = 1.0f / sP;
    const float C00    = g_c00[0];

    // ---- stage scaled x: positions m = l0-2 .. l0+NPX-3 (wrapped mod M) ----
    for (int idx = tid; idx < 2 * NPX; idx += 128) {
        int pidx = idx >> 1, ch = idx & 1;
        int m = l0 - 2 + pidx;
        int mw = m < 0 ? m + M_LEN : (m >= M_LEN ? m - M_LEN : m);
        int g = (b * M_LEN + mw) * 2 + ch;
        s_xr[ch][pidx] = g_xr[g] * sP;
        s_xi[ch][pidx] = g_xi[g] * sP;
    }
    __syncthreads();

    // ---- stage conv series per position m = l0 + idx ----
    for (int idx = tid; idx < NP; idx += 128) {
        const int ix = idx + 2; // x-array index of same position
        float x0r = s_xr[0][ix], x0i = s_xi[0][ix];
        float x1r = s_xr[1][ix], x1i = s_xi[1][ix];
        float p0 = x0r * x0r + x0i * x0i;
        float p1 = x1r * x1r + x1i * x1i;
        S[0 * STR + idx] = 2.f * p0 + p1;
        S[1 * STR + idx] = 2.f * p1 + p0;
        // q[0] = x0 * conj(x1); q[1] = conj(q[0]) (not stored)
        S[2 * STR + idx] = x0r * x1r + x0i * x1i;
        S[3 * STR + idx] = x0i * x1r - x0r * x1i;
        const int ss[4] = {-2, -1, 1, 2};
#pragma unroll
        for (int si = 0; si < 4; ++si) {
            int jx = ix - ss[si]; // x[m - s]
            float a0r = s_xr[0][jx], a0i = s_xi[0][jx];
            float a1r = s_xr[1][jx], a1i = s_xi[1][jx];
            // U_n = x[n] * conj(xs[n])
            float U0r = x0r * a0r + x0i * a0i;
            float U0i = x0i * a0r - x0r * a0i;
            float U1r = x1r * a1r + x1i * a1i;
            float U1i = x1i * a1r - x1r * a1i;
            const int ba = 4 + si * 8;
            // A[n] = 2*U_n + U_{1-n}
            S[(ba + 0) * STR + idx] = 2.f * U0r + U1r;
            S[(ba + 1) * STR + idx] = 2.f * U1r + U0r;
            S[(ba + 2) * STR + idx] = 2.f * U0i + U1i;
            S[(ba + 3) * STR + idx] = 2.f * U1i + U0i;
            // B[n] = x[n] * conj(xs[1-n])
            S[(ba + 4) * STR + idx] = x0r * a1r + x0i * a1i;
            S[(ba + 5) * STR + idx] = x1r * a0r + x1i * a0i;
            S[(ba + 6) * STR + idx] = x0i * a1r - x0r * a1i;
            S[(ba + 7) * STR + idx] = x1i * a0r - x1r * a0i;
        }
    }
    __syncthreads();

    // ---- main conv loop: thread owns outputs l0+4g..l0+4g+3, channel nn ----
    const int g  = tid & 63;
    const int nn = tid >> 6;
    const int r  = g << 2;

    float acc_ix[4] = {0.f, 0.f, 0.f, 0.f};
    float acc_qr[4] = {0.f, 0.f, 0.f, 0.f};
    float acc_qi[4] = {0.f, 0.f, 0.f, 0.f};
    float fAr[4][4] = {}; // [si][o]
    float fAi[4][4] = {};
    float fBr[4][4] = {};
    float fBi[4][4] = {};

    const int a_ps = nn * STR + r;
    const int a_qr = 2 * STR + r;
    const int a_qi = 3 * STR + r;
    int a_Ar[4], a_Ai[4], a_Br[4], a_Bi[4];
#pragma unroll
    for (int si = 0; si < 4; ++si) {
        const int ba = 4 + si * 8;
        a_Ar[si] = (ba + 0 + nn) * STR + r;
        a_Ai[si] = (ba + 2 + nn) * STR + r;
        a_Br[si] = (ba + 4 + nn) * STR + r;
        a_Bi[si] = (ba + 6 + nn) * STR + r;
    }

    float4 p_ps = *(const float4*)&S[a_ps];
    float4 p_qr = *(const float4*)&S[a_qr];
    float4 p_qi = *(const float4*)&S[a_qi];
    float4 p_Ar[4], p_Ai[4], p_Br[4], p_Bi[4];
#pragma unroll
    for (int si = 0; si < 4; ++si) {
        p_Ar[si] = *(const float4*)&S[a_Ar[si]];
        p_Ai[si] = *(const float4*)&S[a_Ai[si]];
        p_Br[si] = *(const float4*)&S[a_Br[si]];
        p_Bi[si] = *(const float4*)&S[a_Bi[si]];
    }

#pragma unroll 1
    for (int bb = 0; bb < 25; ++bb) {
        const int j0 = bb * 8;
        // uniform weights -> scalar loads
        float wxv[8], wcv[8], wrv[4][8], wiv[4][8];
#pragma unroll
        for (int jj = 0; jj < 8; ++jj) {
            wxv[jj] = g_wx[j0 + jj];
            wcv[jj] = g_wc[j0 + jj];
#pragma unroll
            for (int si = 0; si < 4; ++si) {
                wrv[si][jj] = g_wr[si * K_TAPS + j0 + jj];
                wiv[si][jj] = g_wi[si * K_TAPS + j0 + jj];
            }
        }
        // ps
        {
            float4 c  = *(const float4*)&S[a_ps + j0 + 4];
            conv4r(p_ps, c, &wxv[0], acc_ix);
            float4 c2 = *(const float4*)&S[a_ps + j0 + 8];
            conv4r(c, c2, &wxv[4], acc_ix);
            p_ps = c2;
        }
        // q (read once, shared by both channels; conj applied in epilogue)
        {
            float4 c  = *(const float4*)&S[a_qr + j0 + 4];
            conv4r(p_qr, c, &wcv[0], acc_qr);
            float4 c2 = *(const float4*)&S[a_qr + j0 + 8];
            conv4r(c, c2, &wcv[4], acc_qr);
            p_qr = c2;
        }
        {
            float4 c  = *(const float4*)&S[a_qi + j0 + 4];
            conv4r(p_qi, c, &wcv[0], acc_qi);
            float4 c2 = *(const float4*)&S[a_qi + j0 + 8];
            conv4r(c, c2, &wcv[4], acc_qi);
            p_qi = c2;
        }
#pragma unroll
        for (int si = 0; si < 4; ++si) {
            // A
            {
                float4 cr  = *(const float4*)&S[a_Ar[si] + j0 + 4];
                float4 ci  = *(const float4*)&S[a_Ai[si] + j0 + 4];
                conv4c(p_Ar[si], cr, p_Ai[si], ci, &wrv[si][0], &wiv[si][0], fAr[si], fAi[si]);
                float4 cr2 = *(const float4*)&S[a_Ar[si] + j0 + 8];
                float4 ci2 = *(const float4*)&S[a_Ai[si] + j0 + 8];
                conv4c(cr, cr2, ci, ci2, &wrv[si][4], &wiv[si][4], fAr[si], fAi[si]);
                p_Ar[si] = cr2; p_Ai[si] = ci2;
            }
            // B
            {
                float4 cr  = *(const float4*)&S[a_Br[si] + j0 + 4];
                float4 ci  = *(const float4*)&S[a_Bi[si] + j0 + 4];
                conv4c(p_Br[si], cr, p_Bi[si], ci, &wrv[si][0], &wiv[si][0], fBr[si], fBi[si]);
                float4 cr2 = *(const float4*)&S[a_Br[si] + j0 + 8];
                float4 ci2 = *(const float4*)&S[a_Bi[si] + j0 + 8];
                conv4c(cr, cr2, ci, ci2, &wrv[si][4], &wiv[si][4], fBr[si], fBi[si]);
                p_Br[si] = cr2; p_Bi[si] = ci2;
            }
        }
    }

    // ---- tail tap j=200: p_* now hold S[r+200 .. r+203] ----
    {
        const float wx2 = g_wx[200], wc2 = g_wc[200];
#pragma unroll
        for (int o = 0; o < 4; ++o) {
            acc_ix[o] = fmaf(wx2, gw(p_ps, p_ps, o), acc_ix[o]);
            acc_qr[o] = fmaf(wc2, gw(p_qr, p_qr, o), acc_qr[o]);
            acc_qi[o] = fmaf(wc2, gw(p_qi, p_qi, o), acc_qi[o]);
        }
#pragma unroll
        for (int si = 0; si < 4; ++si) {
            const float wr2 = g_wr[si * K_TAPS + 200];
            const float wi2 = g_wi[si * K_TAPS + 200];
#pragma unroll
            for (int o = 0; o < 4; ++o) {
                float vr = gw(p_Ar[si], p_Ar[si], o), vi = gw(p_Ai[si], p_Ai[si], o);
                fAr[si][o] = fmaf(wr2, vr, fmaf(-wi2, vi, fAr[si][o]));
                fAi[si][o] = fmaf(wr2, vi, fmaf( wi2, vr, fAi[si][o]));
                float ur = gw(p_Br[si], p_Br[si], o), ui = gw(p_Bi[si], p_Bi[si], o);
                fBr[si][o] = fmaf(wr2, ur, fmaf(-wi2, ui, fBr[si][o]));
                fBi[si][o] = fmaf(wr2, ui, fmaf( wi2, ur, fBi[si][o]));
            }
        }
    }

    // ---- zero-center-tap correction (zcv only) ----
    {
        const float wx100 = g_wx[T_HALF];
        const float wc100 = g_wc[T_HALF];
        float4 vps = *(const float4*)&S[a_ps + T_HALF];
        float4 vqr = *(const float4*)&S[a_qr + T_HALF];
        float4 vqi = *(const float4*)&S[a_qi + T_HALF];
#pragma unroll
        for (int o = 0; o < 4; ++o) {
            acc_ix[o] = fmaf(-wx100, gw(vps, vps, o), acc_ix[o]);
            acc_qr[o] = fmaf(-wc100, gw(vqr, vqr, o), acc_qr[o]);
            acc_qi[o] = fmaf(-wc100, gw(vqi, vqi, o), acc_qi[o]);
        }
    }

    // ---- epilogue ----
    const int ssf[4] = {-2, -1, 1, 2};
#pragma unroll
    for (int o = 0; o < 4; ++o) {
        const int lrel = r + o;
        const int l = l0 + lrel;
        const int xc = lrel + T_HALF + 2; // x-array index of t+l
        float X0r = s_xr[0][xc], X0i = s_xi[0][xc];
        float X1r = s_xr[1][xc], X1i = s_xi[1][xc];
        float pw  = X0r * X0r + X0i * X0i + X1r * X1r + X1i * X1i;
        float phi = C00 * pw + 2.f * acc_ix[o];
        float sph, cph;
        __sincosf(phi, &sph, &cph);
        // qc for this channel (q[1] = conj(q[0]), real weights)
        float qcr = acc_qr[o];
        float qci = nn ? -acc_qi[o] : acc_qi[o];
        float br_ = nn ? X1r : X0r, bi_ = nn ? X1i : X0i;
        float or_ = nn ? X0r : X1r, oi_ = nn ? X0i : X1i;
        // ici = i * other * qc
        float ici_r = -(or_ * qci + oi_ * qcr);
        float ici_i =   or_ * qcr - oi_ * qci;
        // fwm = sum_si x[t+l-s, nn]*fA + x[t+l-s, 1-nn]*fB
        float fw_r = 0.f, fw_i = 0.f;
#pragma unroll
        for (int si = 0; si < 4; ++si) {
            int sx = xc - ssf[si];
            float xnr  = s_xr[nn][sx],     xni = s_xi[nn][sx];
            float xor_ = s_xr[1 - nn][sx], xoi = s_xi[1 - nn][sx];
            fw_r += xnr * fAr[si][o] - xni * fAi[si][o]
                  + xor_ * fBr[si][o] - xoi * fBi[si][o];
            fw_i += xnr * fAi[si][o] + xni * fAr[si][o]
                  + xor_ * fBi[si][o] + xoi * fBr[si][o];
        }
        float out_r = br_ * cph - bi_ * sph + ici_r + fw_r;
        float out_i = br_ * sph + bi_ * cph + ici_i + fw_i;
        if (l < L_OUT) {
            int oidx = (((b * L_OUT) + l) * 2 + nn) * 2;
            g_out[oidx]     = out_r * inv_sP;
            g_out[oidx + 1] = out_i * inv_sP;
        }
    }
}

extern "C" void kernel_launch(void* const* d_in, const int* in_sizes, int n_in,
                              void* d_out, int out_size, void* d_ws, size_t ws_size,
                              hipStream_t stream) {
    const float* xr  = (const float*)d_in[0];
    const float* xi  = (const float*)d_in[1];
    const float* ti  = (const float*)d_in[2];
    const float* c00 = (const float*)d_in[3];
    const float* wx  = (const float*)d_in[4];
    const float* wc  = (const float*)d_in[5];
    const float* wr  = (const float*)d_in[6];
    const float* wi  = (const float*)d_in[7];
    float* out = (float*)d_out;

    dim3 grid(NTILES, B_SZ, 1);
    dim3 block(128, 1, 1);
    snse_kernel<<<grid, block, 0, stream>>>(xr, xi, ti, c00, wx, wc, wr, wi, out);
}